// Round 4
// baseline (1363.719 us; speedup 1.0000x reference)
//
#include <hip/hip_runtime.h>

#define B 100
#define R 1152
#define C 10
#define O 16
#define I 8
#define RI 9216      // R*I
#define CO 160       // C*O
#define RCHUNK 32
#define NRC 36       // R / RCHUNK
#define KCH (RCHUNK*I)  // 256

#define NB 360       // routing-team blocks
#define GRID 1024    // total blocks (4/CU x 256 CU, fully resident)
#define NSTREAM (GRID - NB)

typedef float f4raw __attribute__((ext_vector_type(4)));
__device__ __forceinline__ void nt_store4(const float4& v, float4* p) {
    __builtin_nontemporal_store(*(const f4raw*)&v, (f4raw*)p);
}

// ws offsets (in floats)
#define WS_BCOL 0                  // 11520  b_ij stored [c][r]
#define WS_CSM  11520              // 11520  softmax c_ij stored [r][c]
#define WS_XT   23040              // 921600 + 128 pad: xT[k][b], k=r*8+i
#define WS_PART 944768             // 10*36*100*16 = 576000 partial s_j
#define WS_V    1520768            // 16000  v_j [b][c][o]
#define WS_SMUT 1536768            // 16000  s_mut [b][c][o]
#define WS_CNT  1552768            // barrier counter (uint), zeroed via memsetAsync

// out float4 offsets: v_j 0 | c_full 4000 | Wb 292000 | squashed_u 37156000 |
// x1 39460000 | x2 39690400 | s_mut 39710000 | end 39714000
#define WB_OUT_BASE 292000
#define WB_WSTRIDE  368640
#define WB_NCHUNK   1440
#define WB_BG       20
#define WB_UNITS    7200           // 5 bgroups x 1440 wchunks, 80KB each

__device__ __forceinline__ void wb_unit(const float4* __restrict__ W4,
                                        float4* __restrict__ out, int unit) {
    int wchunk = unit % WB_NCHUNK;
    int bg = unit / WB_NCHUNK;
    int idx = wchunk * 256 + threadIdx.x;
    float4 v = W4[idx];
    float4* dst = out + WB_OUT_BASE + (size_t)bg * WB_BG * WB_WSTRIDE + idx;
    #pragma unroll
    for (int b = 0; b < WB_BG; b++) {
        nt_store4(v, dst);
        dst += WB_WSTRIDE;
    }
}

// ---- device-scope monotone barrier among the NB routing blocks ----
__device__ __forceinline__ void rbar(unsigned* cnt, unsigned target) {
    __syncthreads();
    if (threadIdx.x == 0) {
        __hip_atomic_fetch_add(cnt, 1u, __ATOMIC_ACQ_REL, __HIP_MEMORY_SCOPE_AGENT);
        while (__hip_atomic_load(cnt, __ATOMIC_ACQUIRE, __HIP_MEMORY_SCOPE_AGENT) < target)
            __builtin_amdgcn_s_sleep(2);
    }
    __syncthreads();
    __threadfence();
}

// ---- phase: GEMM1 (softmax fused), one (rc,c) unit per routing block ----
__device__ __forceinline__ void phase_gemm1(int bk, int t, const float* __restrict__ Wg,
                                            float* __restrict__ ws, char* smem) {
    const int rc = bk % NRC, c = bk / NRC;
    const int r0 = rc * RCHUNK;
    float* red = (float*)smem;        // 256
    float* cw  = red + 256;           // 32
    float* lw  = cw + 32;             // 4096  [k][o], c-weight folded
    const float* bcol = ws + WS_BCOL + c * R;

    float lm = -3.4e38f;
    for (int r = t; r < R; r += 256) lm = fmaxf(lm, bcol[r]);
    red[t] = lm; __syncthreads();
    for (int s = 128; s > 0; s >>= 1) { if (t < s) red[t] = fmaxf(red[t], red[t + s]); __syncthreads(); }
    const float m = red[0]; __syncthreads();
    float ls = 0.f;
    for (int r = t; r < R; r += 256) ls += expf(bcol[r] - m);
    red[t] = ls; __syncthreads();
    for (int s = 128; s > 0; s >>= 1) { if (t < s) red[t] += red[t + s]; __syncthreads(); }
    const float sinv = 1.f / red[0];
    if (t < RCHUNK) {
        float w_ = expf(bcol[r0 + t] - m) * sinv;
        cw[t] = w_;
        ws[WS_CSM + (r0 + t) * C + c] = w_;
    }
    __syncthreads();

    for (int j = t; j < KCH * O; j += 256) {
        int rr = j >> 7;
        int rem = j & 127;            // o*8+i
        int o = rem >> 3, i = rem & 7;
        lw[(rr * I + i) * O + o] = cw[rr] * Wg[((size_t)(r0 + rr) * C + c) * (O * I) + rem];
    }
    __syncthreads();

    const int bl = t & 63, og = t >> 6;
    const float* xT = ws + WS_XT + (r0 * I) * B + bl;
    const float4* lw4 = (const float4*)lw;
    float4 a0 = {0, 0, 0, 0}, a1 = {0, 0, 0, 0};
    #pragma unroll 8
    for (int k = 0; k < KCH; k++) {
        float xv0 = xT[0];
        float xv1 = xT[64];           // pad after xT keeps this in-bounds
        float4 wv = lw4[k * 4 + og];
        a0.x += xv0 * wv.x; a0.y += xv0 * wv.y; a0.z += xv0 * wv.z; a0.w += xv0 * wv.w;
        a1.x += xv1 * wv.x; a1.y += xv1 * wv.y; a1.z += xv1 * wv.z; a1.w += xv1 * wv.w;
        xT += B;
    }
    float4* part4 = (float4*)(ws + WS_PART);
    int base = ((c * NRC + rc) * B + bl) * 4 + og;
    part4[base] = a0;
    if (bl < B - 64) part4[base + 64 * 4] = a1;
    __syncthreads();   // smem reused next phase
}

// ---- phase: reduce partials + squash, block bk = batch b (bk < B) ----
__device__ __forceinline__ void phase_squash(int b, int t, float* __restrict__ ws, char* smem) {
    float* sl = (float*)smem;   // 160
    float* nf = sl + 160;       // 10
    if (t < CO) {
        int c = t >> 4, o = t & 15;
        float s = 0.f;
        const float* p = ws + WS_PART + ((size_t)c * NRC * B + b) * 16 + o;
        #pragma unroll
        for (int rc = 0; rc < NRC; rc++) s += p[(size_t)rc * B * 16];
        sl[t] = s;
    }
    __syncthreads();
    if (t < C) {
        float fv[C];
        #pragma unroll
        for (int c2 = 0; c2 < C; c2++) fv[c2] = sl[c2 * O];
        float mine = sl[t * O];
        int rank = 0, i1 = 0, i2 = 0, i3 = 0;
        #pragma unroll
        for (int c2 = 0; c2 < C; c2++) {
            rank += (fv[c2] < mine) || (fv[c2] == mine && c2 < t);
            i1 += fv[c2] < -0.075410217f;
            i2 += fv[c2] < 0.0f;
            i3 += fv[c2] < 0.062207676f;
        }
        float nv = mine;
        if (i1 > 0 && rank < i1 - 1)                               nv = -0.074520095f * mine + 0.349297946f;
        else if (i2 > 0 && i2 > i1 && rank >= i1 && rank < i2 - 1) nv = -0.534473989f * mine + 0.27196494f;
        else if (i3 > 0 && i3 > i2 && rank >= i2 && rank < i3 - 1) nv = 0.637642944f * mine + 0.295330779f;
        else if (i3 < C && rank >= i3 && rank < C - 1)             nv = 0.169344703f * mine + 0.353784456f;
        nf[t] = nv;
    }
    __syncthreads();
    if (t < CO) {
        int c = t >> 4, o = t & 15;
        float sv = sl[t];
        float nfv = nf[c];
        float smut = (o == 0) ? nfv : sv;
        ws[WS_SMUT + b * CO + t] = smut;
        ws[WS_V + b * CO + t] = nfv * smut;
    }
    __syncthreads();
}

// ---- phase: agreement for one r ----
__device__ __forceinline__ void phase_agree(int r, int t, const float* __restrict__ Wg,
                                            float* __restrict__ ws, char* smem) {
    float* vt  = (float*)smem;    // 3200 [cc][b]
    float* xs  = vt + 3200;       // 800  [i][b]
    float* arr = xs + 800;        // 1280 [co][i]
    for (int j = t; j < I * B; j += 256) xs[j] = ws[WS_XT + (size_t)r * I * B + j];
    const int i = t & 7, co0 = t >> 3;
    const float4* xs4 = (const float4*)(xs + i * B);
    const float4* vt4 = (const float4*)(vt + co0 * B);
    for (int ch = 0; ch < 5; ch++) {
        __syncthreads();
        for (int j = t; j < 32 * B; j += 256) {
            int b = j >> 5, cc = j & 31;
            vt[cc * B + b] = ws[WS_V + b * CO + ch * 32 + cc];
        }
        __syncthreads();
        float q = 0.f;
        #pragma unroll
        for (int b4 = 0; b4 < B / 4; b4++) {
            float4 xv = xs4[b4];
            float4 vv = vt4[b4];
            q += xv.x * vv.x + xv.y * vv.y + xv.z * vv.z + xv.w * vv.w;
        }
        int co = ch * 32 + co0;
        arr[co * I + i] = q * Wg[(size_t)r * (C * O * I) + co * I + i];
    }
    __syncthreads();
    if (t < C) {
        const float4* a4 = (const float4*)(arr + t * 128);
        float d = 0.f;
        #pragma unroll
        for (int m2 = 0; m2 < 32; m2++) { float4 v4 = a4[m2]; d += v4.x + v4.y + v4.z + v4.w; }
        ws[WS_BCOL + t * R + r] += d * (1.0f / B);
    }
    __syncthreads();
}

// ---- the single persistent kernel ----
__global__ __launch_bounds__(256, 4) void k_all(const float* __restrict__ x0,
                                                const float* __restrict__ x1,
                                                const float* __restrict__ x2,
                                                const float* __restrict__ Wg,
                                                float* __restrict__ ws,
                                                float4* __restrict__ out) {
    const int bid = blockIdx.x, t = threadIdx.x;
    __shared__ __align__(16) char smem[21504];
    unsigned* cnt = (unsigned*)(ws + WS_CNT);
    const float4* W4 = (const float4*)Wg;

    if (bid >= NB) {
        // ---------------- streamer team: independent 631 MB ----------------
        int s = bid - NB;   // 0..663
        #pragma unroll 1
        for (int u = 0; u < 10; u++)
            wb_unit(W4, out, s * 10 + u);          // units 0..6639
        const float4* x04 = (const float4*)x0;
        const float4* x14 = (const float4*)x1;
        const float4* x24 = (const float4*)x2;
        int s0 = s * 3847;
        int s1 = s0 + 3847; if (s1 > 2554000) s1 = 2554000;
        for (int m = s0 + t; m < s1; m += 256) {
            float4 v; int g;
            if (m < 2304000) {                      // squashed_u: x0 bcast over c
                int q = m / 20;
                v = x04[q * 2 + (m & 1)];
                g = 37156000 + m;
            } else if (m < 2534400) {               // x1 copy
                v = x14[m - 2304000]; g = 39460000 + (m - 2304000);
            } else {                                // x2 copy
                v = x24[m - 2534400]; g = 39690400 + (m - 2534400);
            }
            nt_store4(v, &out[g]);
        }
        return;
    }

    // ---------------- routing team: blocks 0..359 ----------------
    const int bk = bid;
    {   // p0: transpose x0 -> xT (LDS-tiled), zero bcol
        float (*tp)[104] = (float (*)[104])smem;
        for (int tile = bk; tile < 288; tile += NB) {
            int k0 = tile * 32;
            for (int e = t; e < 3200; e += 256) {
                int b = e >> 5, kk = e & 31;
                tp[kk][b] = x0[(size_t)b * RI + k0 + kk];
            }
            __syncthreads();
            for (int e = t; e < 3200; e += 256) {
                int kk = e / 100, b = e - kk * 100;
                ws[WS_XT + (size_t)(k0 + kk) * B + b] = tp[kk][b];
            }
            __syncthreads();
        }
        if (bk < 45) ws[WS_BCOL + bk * 256 + t] = 0.f;
    }
    rbar(cnt, NB * 1);

    for (int it = 0; it < 3; it++) {
        phase_gemm1(bk, t, Wg, ws, smem);
        rbar(cnt, NB * (2 + it * 3));
        if (bk < B) phase_squash(bk, t, ws, smem);
        rbar(cnt, NB * (3 + it * 3));
        if (it < 2) {
            for (int r = bk; r < R; r += NB) phase_agree(r, t, Wg, ws, smem);
            rbar(cnt, NB * (4 + it * 3));
        }
    }

    {   // final: v_j | c_full | s_mut, then help with Wb tail
        const float4* v4  = (const float4*)(ws + WS_V);
        const float4* cs4 = (const float4*)(ws + WS_CSM);
        const float4* sm4 = (const float4*)(ws + WS_SMUT);
        for (int j = bk * 256 + t; j < 296000; j += NB * 256) {
            float4 v; int g;
            if (j < 4000)        { v = v4[j]; g = j; }
            else if (j < 292000) { int q = j - 4000; v = cs4[q % 2880]; g = j; }
            else                 { int q = j - 292000; v = sm4[q]; g = 39710000 + q; }
            nt_store4(v, &out[g]);
        }
        wb_unit(W4, out, 6640 + bk);                 // units 6640..6999
        if (bk < 200) wb_unit(W4, out, 7000 + bk);   // units 7000..7199
    }
}

extern "C" void kernel_launch(void* const* d_in, const int* in_sizes, int n_in,
                              void* d_out, int out_size, void* d_ws, size_t ws_size,
                              hipStream_t stream) {
    (void)in_sizes; (void)n_in; (void)out_size; (void)ws_size;
    const float* x0 = (const float*)d_in[0];
    const float* x1 = (const float*)d_in[1];
    const float* x2 = (const float*)d_in[2];
    const float* Wg = (const float*)d_in[3];
    float* ws = (float*)d_ws;
    float4* out = (float4*)d_out;

    // zero the barrier counter (captured into the graph, replayed every call)
    hipMemsetAsync((char*)d_ws + (size_t)WS_CNT * 4, 0, 64, stream);
    hipLaunchKernelGGL(k_all, dim3(GRID), dim3(256), 0, stream, x0, x1, x2, Wg, ws, out);
}

// Round 5
// 340.616 us; speedup vs baseline: 4.0037x; 4.0037x over previous
//
#include <hip/hip_runtime.h>

#define B 100
#define R 1152
#define C 10
#define O 16
#define I 8
#define RI 9216      // R*I
#define RCHUNK 32
#define NRC 36       // R / RCHUNK
#define KCH (RCHUNK*I)  // 256

#define T1c (-0.075410217f)
#define T3c (0.062207676f)

typedef float f4raw __attribute__((ext_vector_type(4)));
__device__ __forceinline__ void nt_store4(const float4& v, float4* p) {
    __builtin_nontemporal_store(*(const f4raw*)&v, (f4raw*)p);
}

// ws float offsets
#define WS_Q    0                  // uint work-queue counter (zeroed per call)
#define WS_SJ   64                 // 3 * 16000 s_j buffers [it][c][b][o] (zeroed per call)
#define WS_BCOL 48128              // [c][r]
#define WS_CSM  59648              // [r][c]
#define WS_XT   103232             // [k][b], k=r*8+i, + 128 pad
#define MEMSET_BYTES ((WS_SJ + 48000) * 4)

// out float4 offsets: v_j 0 | c_full 4000 | Wb 292000 | squashed_u 37156000 |
// x1 39460000 | x2 39690400 | s_mut 39710000 | end 39714000
#define WB_OUT_BASE 292000
#define WB_WSTRIDE  368640
#define WB_NCHUNK   1440
#define WB_BG       20
#define WB_UNITS    7200           // 7200 units x 80KB = full Wb broadcast

__device__ __forceinline__ void wb_unit(const float4* __restrict__ W4,
                                        float4* __restrict__ out, int unit) {
    int wchunk = unit % WB_NCHUNK;
    int bg = unit / WB_NCHUNK;
    int idx = wchunk * 256 + threadIdx.x;
    float4 v = W4[idx];
    float4* dst = out + WB_OUT_BASE + (size_t)bg * WB_BG * WB_WSTRIDE + idx;
    #pragma unroll
    for (int b = 0; b < WB_BG; b++) { nt_store4(v, dst); dst += WB_WSTRIDE; }
}

// bounded cooperative drain of the Wb queue (no spinning: each grab does work)
__device__ __forceinline__ void rider(float* ws, const float4* __restrict__ W4,
                                      float4* __restrict__ out, int cap) {
    __shared__ unsigned su;
    unsigned* q = (unsigned*)ws;    // WS_Q
    for (int n = 0; n < cap; n++) {
        if (threadIdx.x == 0) su = atomicAdd(q, 1u);
        __syncthreads();
        unsigned u = su;
        __syncthreads();
        if (u >= WB_UNITS) return;
        wb_unit(W4, out, u);
    }
}

// squash piecewise map for f[c][b]; fbase[(c2*100+b)*stride] = f values
__device__ __forceinline__ float squash_nf(const float* fbase, int stride, int c, int b) {
    float mine = fbase[(c * 100 + b) * stride];
    int rank = 0, i1 = 0, i2 = 0, i3 = 0;
    #pragma unroll
    for (int c2 = 0; c2 < C; c2++) {
        float f2 = fbase[(c2 * 100 + b) * stride];
        rank += (f2 < mine) || (f2 == mine && c2 < c);
        i1 += f2 < T1c;
        i2 += f2 < 0.0f;
        i3 += f2 < T3c;
    }
    float nv = mine;
    if (i1 > 0 && rank < i1 - 1)                               nv = -0.074520095f * mine + 0.349297946f;
    else if (i2 > 0 && i2 > i1 && rank >= i1 && rank < i2 - 1) nv = -0.534473989f * mine + 0.27196494f;
    else if (i3 > 0 && i3 > i2 && rank >= i2 && rank < i3 - 1) nv = 0.637642944f * mine + 0.295330779f;
    else if (i3 < C && rank >= i3 && rank < C - 1)             nv = 0.169344703f * mine + 0.353784456f;
    return nv;
}

// ---------- L0: transpose x0 -> xT; + riders ----------
__global__ __launch_bounds__(256) void k_init(const float* __restrict__ x0,
                                              float* __restrict__ ws,
                                              const float4* __restrict__ W4,
                                              float4* __restrict__ out) {
    if (blockIdx.x >= 288) { rider(ws, W4, out, 2); return; }
    __shared__ float tp[32][105];
    const int t = threadIdx.x;
    const int k0 = blockIdx.x * 32;
    for (int e = t; e < 3200; e += 256) {
        int b = e >> 5, kk = e & 31;
        tp[kk][b] = x0[(size_t)b * RI + k0 + kk];
    }
    __syncthreads();
    for (int e = t; e < 3200; e += 256) {
        int kk = e / 100, b = e - kk * 100;
        ws[WS_XT + (size_t)(k0 + kk) * B + b] = tp[kk][b];
    }
}

// ---------- G: s_j GEMM with atomic accumulation; softmax fused (it>0) ----------
__global__ __launch_bounds__(256) void k_gemm(const float* __restrict__ Wg,
                                              float* __restrict__ ws,
                                              float4* __restrict__ out, int it) {
    const int t = threadIdx.x;
    if (blockIdx.x >= 360) { rider(ws, (const float4*)Wg, out, 2); return; }
    const int rc = blockIdx.x % NRC, c = blockIdx.x / NRC;
    const int r0 = rc * RCHUNK;
    __shared__ float red[256];
    __shared__ float cw[RCHUNK];
    __shared__ __align__(16) float lw[KCH * O];

    if (it > 0) {
        const float* bcol = ws + WS_BCOL + c * R;
        float lm = -3.4e38f;
        for (int r = t; r < R; r += 256) lm = fmaxf(lm, bcol[r]);
        red[t] = lm; __syncthreads();
        for (int s = 128; s > 0; s >>= 1) { if (t < s) red[t] = fmaxf(red[t], red[t + s]); __syncthreads(); }
        const float m = red[0]; __syncthreads();
        float ls = 0.f;
        for (int r = t; r < R; r += 256) ls += expf(bcol[r] - m);
        red[t] = ls; __syncthreads();
        for (int s = 128; s > 0; s >>= 1) { if (t < s) red[t] += red[t + s]; __syncthreads(); }
        const float sinv = 1.f / red[0];
        if (t < RCHUNK) cw[t] = expf(bcol[r0 + t] - m) * sinv;
        if (it == 2 && rc == 0) {   // final c_ij for the c_full output
            for (int r = t; r < R; r += 256)
                ws[WS_CSM + r * C + c] = expf(bcol[r] - m) * sinv;
        }
    } else {
        if (t < RCHUNK) cw[t] = 1.0f / 1152.0f;   // softmax of zeros
    }
    __syncthreads();

    // stage c-weighted W slice: lw[(rr*8+i)*16+o] = cw[rr]*W[r0+rr,c,o,i]
    for (int j = t; j < KCH * O; j += 256) {
        int rr = j >> 7;
        int rem = j & 127;            // o*8+i
        int o = rem >> 3, i = rem & 7;
        lw[(rr * I + i) * O + o] = cw[rr] * Wg[((size_t)(r0 + rr) * C + c) * 128 + rem];
    }
    __syncthreads();

    const int bl = t & 63, og = t >> 6;
    const float* xT = ws + WS_XT + (r0 * I) * B + bl;
    const float4* lw4 = (const float4*)lw;
    float4 a0 = {0, 0, 0, 0}, a1 = {0, 0, 0, 0};
    #pragma unroll 8
    for (int k = 0; k < KCH; k++) {
        float xv0 = xT[0];
        float xv1 = xT[64];           // pad after xT keeps this in-bounds
        float4 wv = lw4[k * 4 + og];
        a0.x += xv0 * wv.x; a0.y += xv0 * wv.y; a0.z += xv0 * wv.z; a0.w += xv0 * wv.w;
        a1.x += xv1 * wv.x; a1.y += xv1 * wv.y; a1.z += xv1 * wv.z; a1.w += xv1 * wv.w;
        xT += B;
    }
    float* sj = ws + WS_SJ + it * 16000;
    int base = (c * B + bl) * O + og * 4;
    atomicAdd(&sj[base + 0], a0.x); atomicAdd(&sj[base + 1], a0.y);
    atomicAdd(&sj[base + 2], a0.z); atomicAdd(&sj[base + 3], a0.w);
    if (bl < B - 64) {
        int b2 = base + 64 * O;
        atomicAdd(&sj[b2 + 0], a1.x); atomicAdd(&sj[b2 + 1], a1.y);
        atomicAdd(&sj[b2 + 2], a1.z); atomicAdd(&sj[b2 + 3], a1.w);
    }
}

// ---------- A: inline squash + agreement; one block per r ----------
__global__ __launch_bounds__(256) void k_agree(const float* __restrict__ Wg,
                                               float* __restrict__ ws,
                                               float4* __restrict__ out, int it) {
    const int t = threadIdx.x;
    if (blockIdx.x >= R) { rider(ws, (const float4*)Wg, out, 2); return; }
    const int r = blockIdx.x;
    __shared__ __align__(16) float vt[3200];   // [cc][b]
    __shared__ __align__(16) float xs[800];    // [i][b]
    __shared__ __align__(16) float arr[1280];  // [co][i]
    __shared__ float fs[1000];                 // f[c][b]
    __shared__ float nfs[1000];                // new_f[c][b]
    const float* sj = ws + WS_SJ + it * 16000;

    for (int j = t; j < 800; j += 256) xs[j] = ws[WS_XT + (size_t)r * 800 + j];
    for (int j = t; j < 1000; j += 256) fs[j] = sj[j * 16];
    __syncthreads();
    for (int j = t; j < 1000; j += 256) nfs[j] = squash_nf(fs, 1, j / 100, j % 100);
    __syncthreads();

    const int i = t & 7, co0 = t >> 3;
    const float4* xs4 = (const float4*)(xs + i * B);
    const float4* vt4 = (const float4*)(vt + co0 * B);
    for (int ch = 0; ch < 5; ch++) {
        if (ch) __syncthreads();
        for (int j = t; j < 3200; j += 256) {
            int b = j >> 5, cc = j & 31;
            int co = ch * 32 + cc, c2 = co >> 4, o = co & 15;
            int cb = c2 * 100 + b;
            float nfv = nfs[cb];
            float sv = sj[cb * 16 + o];
            vt[cc * B + b] = nfv * ((o == 0) ? nfv : sv);   // v[b][c2][o]
        }
        __syncthreads();
        float q = 0.f;
        #pragma unroll
        for (int b4 = 0; b4 < B / 4; b4++) {
            float4 xv = xs4[b4];
            float4 vv = vt4[b4];
            q += xv.x * vv.x + xv.y * vv.y + xv.z * vv.z + xv.w * vv.w;
        }
        int co = ch * 32 + co0;
        arr[co * I + i] = q * Wg[(size_t)r * 1280 + co * I + i];
    }
    __syncthreads();
    if (t < C) {
        const float4* a4 = (const float4*)(arr + t * 128);
        float d = 0.f;
        #pragma unroll
        for (int m2 = 0; m2 < 32; m2++) { float4 v4 = a4[m2]; d += v4.x + v4.y + v4.z + v4.w; }
        float* dst = ws + WS_BCOL + t * R + r;
        float val = d * (1.0f / B);
        if (it == 0) *dst = val; else *dst += val;
    }
}

// ---------- OUT: fixed regions (v/c_full/squashed_u/x1/x2/s_mut) + queue drain ----------
#define OUT_BLOCKS 2400
__global__ __launch_bounds__(256) void k_out(const float* __restrict__ x0,
                                             const float* __restrict__ x1,
                                             const float* __restrict__ x2,
                                             float* __restrict__ ws,
                                             const float4* __restrict__ W4,
                                             float4* __restrict__ out) {
    const float4* x04 = (const float4*)x0;
    const float4* x14 = (const float4*)x1;
    const float4* x24 = (const float4*)x2;
    const float4* cs4 = (const float4*)(ws + WS_CSM);
    const float* sj2 = ws + WS_SJ + 2 * 16000;
    const int stride = OUT_BLOCKS * 256;
    for (int u = blockIdx.x * 256 + threadIdx.x; u < 2850000; u += stride) {
        int g = (u < 292000) ? u : u + 36864000;   // skip Wb region
        float4 val;
        if (g >= 37156000 && g < 39460000) {        // squashed_u: x0 bcast over c
            int j = g - 37156000;
            val = x04[(j / 20) * 2 + (j & 1)];
        } else if (g >= 4000 && g < 292000) {       // c_full
            val = cs4[(g - 4000) % 2880];
        } else if (g < 4000) {                      // v_j = nf * s_mut
            int fi = g * 4;
            int b = fi / 160, rem = fi % 160, c = rem >> 4, o = rem & 15;
            float nf = squash_nf(sj2, 16, c, b);
            const float* sp = sj2 + (c * 100 + b) * 16 + o;
            val.x = nf * ((o == 0) ? nf : sp[0]);
            val.y = nf * sp[1]; val.z = nf * sp[2]; val.w = nf * sp[3];
        } else if (g < 39690400) {                  // x1 copy
            val = x14[g - 39460000];
        } else if (g < 39710000) {                  // x2 copy
            val = x24[g - 39690400];
        } else {                                    // s_mut
            int fi = (g - 39710000) * 4;
            int b = fi / 160, rem = fi % 160, c = rem >> 4, o = rem & 15;
            float nf = squash_nf(sj2, 16, c, b);
            const float* sp = sj2 + (c * 100 + b) * 16 + o;
            val.x = (o == 0) ? nf : sp[0];
            val.y = sp[1]; val.z = sp[2]; val.w = sp[3];
        }
        nt_store4(val, &out[g]);
    }
    rider(ws, W4, out, 12);   // drain remaining Wb units (backstop)
}

extern "C" void kernel_launch(void* const* d_in, const int* in_sizes, int n_in,
                              void* d_out, int out_size, void* d_ws, size_t ws_size,
                              hipStream_t stream) {
    (void)in_sizes; (void)n_in; (void)out_size; (void)ws_size;
    const float* x0 = (const float*)d_in[0];
    const float* x1 = (const float*)d_in[1];
    const float* x2 = (const float*)d_in[2];
    const float* Wg = (const float*)d_in[3];
    const float4* W4 = (const float4*)Wg;
    float* ws = (float*)d_ws;
    float4* out = (float4*)d_out;

    // zero queue + s_j accumulators (captured; replayed every call)
    hipMemsetAsync(d_ws, 0, MEMSET_BYTES, stream);
    hipLaunchKernelGGL(k_init, dim3(288 + 320), dim3(256), 0, stream, x0, ws, W4, out);
    hipLaunchKernelGGL(k_gemm, dim3(360 + 480), dim3(256), 0, stream, Wg, ws, out, 0);
    hipLaunchKernelGGL(k_agree, dim3(R + 480), dim3(256), 0, stream, Wg, ws, out, 0);
    hipLaunchKernelGGL(k_gemm, dim3(360 + 480), dim3(256), 0, stream, Wg, ws, out, 1);
    hipLaunchKernelGGL(k_agree, dim3(R + 480), dim3(256), 0, stream, Wg, ws, out, 1);
    hipLaunchKernelGGL(k_gemm, dim3(360 + 480), dim3(256), 0, stream, Wg, ws, out, 2);
    hipLaunchKernelGGL(k_out, dim3(OUT_BLOCKS), dim3(256), 0, stream, x0, x1, x2, ws, W4, out);
}

// Round 6
// 226.977 us; speedup vs baseline: 6.0082x; 1.5007x over previous
//
#include <hip/hip_runtime.h>

#define B 100
#define R 1152
#define C 10
#define O 16
#define I 8
#define RI 9216
#define RC2 2304        // x0 row length in float4
#define RCHUNK 16
#define NRC 72          // R / RCHUNK
#define KCH 128         // RCHUNK*I

#define T1c (-0.075410217f)
#define T3c (0.062207676f)

typedef float f4raw __attribute__((ext_vector_type(4)));
static __device__ __forceinline__ void nt_store4(const float4& v, float4* p) {
    __builtin_nontemporal_store(*(const f4raw*)&v, (f4raw*)p);
}

// ws float offsets (total 1,223,040 floats = 4.89 MB)
#define WS_BCOL 0                  // [c][r] 11520
#define WS_CSM  11520              // [r][c] 11520
#define WS_PART 23040              // [c][rc][b][o] 10*72*100*16 = 1152000
#define WS_VOB  1175040            // [c*16+o][b] 16000 (coalesced A staging)
#define WS_VBCO 1191040            // [b][c][o] 16000
#define WS_SMUT 1207040            // [b][c][o] 16000

// out float4 offsets
#define O_VJ 0
#define O_CF 4000
#define O_WB 292000
#define O_SQ 37156000
#define O_X1 39460000
#define O_X2 39690400
#define O_SM 39710000

// static stream units: Wb 7200 x 80KB | squashed_u 563 x 64KB | x1 57 | x2 5
#define U_WB 7200
#define U_SQ 563
#define U_X1 57
#define U_X2 5
#define U_TOT 7825

__device__ void stream_unit(int u, const float4* __restrict__ W4,
                            const float4* __restrict__ x04,
                            const float4* __restrict__ x14,
                            const float4* __restrict__ x24,
                            float4* __restrict__ out) {
    const int t = threadIdx.x;
    if (u < U_WB) {
        int wchunk = u % 1440, bg = u / 1440;
        int idx = wchunk * 256 + t;
        float4 v = W4[idx];
        float4* dst = out + O_WB + (size_t)bg * 20 * 368640 + idx;
        #pragma unroll
        for (int b = 0; b < 20; b++) { nt_store4(v, dst); dst += 368640; }
    } else if (u < U_WB + U_SQ) {
        int s = u - U_WB;
        int m0 = s * 4096, m1 = m0 + 4096; if (m1 > 2304000) m1 = 2304000;
        for (int m = m0 + t; m < m1; m += 256) {
            float4 v = x04[(m / 20) * 2 + (m & 1)];   // squashed_u = x0 bcast over c
            nt_store4(v, &out[O_SQ + m]);
        }
    } else if (u < U_WB + U_SQ + U_X1) {
        int s = u - U_WB - U_SQ;
        int m0 = s * 4096, m1 = m0 + 4096; if (m1 > 230400) m1 = 230400;
        for (int m = m0 + t; m < m1; m += 256) nt_store4(x14[m], &out[O_X1 + m]);
    } else {
        int s = u - U_WB - U_SQ - U_X1;
        int m0 = s * 4096, m1 = m0 + 4096; if (m1 > 19600) m1 = 19600;
        for (int m = m0 + t; m < m1; m += 256) nt_store4(x24[m], &out[O_X2 + m]);
    }
}

// ---------- G: s_j partial GEMM, softmax fused, private x0 transpose ----------
__global__ __launch_bounds__(256) void k_gemm(const float* __restrict__ Wg,
                                              const float* __restrict__ x0,
                                              float* __restrict__ ws,
                                              const float4* __restrict__ x14,
                                              const float4* __restrict__ x24,
                                              float4* __restrict__ out,
                                              int it, int ubase) {
    const int t = threadIdx.x;
    const float4* x04 = (const float4*)x0;
    if (blockIdx.x >= 720) {
        int k = blockIdx.x - 720;
        #pragma unroll 1
        for (int n = 0; n < 3; n++)
            stream_unit(ubase + k * 3 + n, (const float4*)Wg, x04, x14, x24, out);
        return;
    }
    const int rc = blockIdx.x % NRC, c = blockIdx.x / NRC;
    const int r0 = rc * RCHUNK;
    __shared__ float red[256];
    __shared__ float cw[RCHUNK];
    __shared__ __align__(16) float lw[KCH * O];   // 2048: [k][o], c-weight folded
    __shared__ float tp[64][104];                 // x0 transpose tile [k][b]

    if (it > 0) {
        const float* bcol = ws + WS_BCOL + c * R;
        float lm = -3.4e38f;
        for (int r = t; r < R; r += 256) lm = fmaxf(lm, bcol[r]);
        red[t] = lm; __syncthreads();
        for (int s = 128; s > 0; s >>= 1) { if (t < s) red[t] = fmaxf(red[t], red[t + s]); __syncthreads(); }
        const float m = red[0]; __syncthreads();
        float ls = 0.f;
        for (int r = t; r < R; r += 256) ls += expf(bcol[r] - m);
        red[t] = ls; __syncthreads();
        for (int s = 128; s > 0; s >>= 1) { if (t < s) red[t] += red[t + s]; __syncthreads(); }
        const float sinv = 1.f / red[0];
        if (t < RCHUNK) cw[t] = expf(bcol[r0 + t] - m) * sinv;
        if (it == 2 && rc == 0) {   // final c_ij for the c_full output
            for (int r = t; r < R; r += 256)
                ws[WS_CSM + r * C + c] = expf(bcol[r] - m) * sinv;
        }
    } else {
        if (t < RCHUNK) cw[t] = 1.0f / 1152.0f;   // softmax of zeros
    }
    __syncthreads();

    // stage c-weighted W slice: lw[(rr*8+i)*16+o] = cw[rr]*W[r0+rr,c,o,i]
    for (int j = t; j < KCH * O; j += 256) {
        int rr = j >> 7;
        int rem = j & 127;            // o*8+i
        int o = rem >> 3, i = rem & 7;
        lw[((rr * I + i) << 4) + o] = cw[rr] * Wg[((size_t)(r0 + rr) * C + c) * 128 + rem];
    }

    const int bl = t & 63, og = t >> 6;
    int b2 = bl + 64; if (b2 > 103) b2 = 103;    // clamps into zero pad
    float4 a0 = {0, 0, 0, 0}, a1 = {0, 0, 0, 0};
    for (int p = 0; p < 2; p++) {
        __syncthreads();
        int colbase = r0 * 2 + p * 16;           // f4 column base in x0 row
        for (int e = t; e < 1600; e += 256) {
            int b = e >> 4, q = e & 15;
            float4 v = x04[(size_t)b * RC2 + colbase + q];
            tp[q * 4 + 0][b] = v.x; tp[q * 4 + 1][b] = v.y;
            tp[q * 4 + 2][b] = v.z; tp[q * 4 + 3][b] = v.w;
        }
        tp[t >> 2][100 + (t & 3)] = 0.f;         // zero pad cols 100..103
        __syncthreads();
        const float4* lwp = (const float4*)lw + p * 64 * 4;
        #pragma unroll 8
        for (int k = 0; k < 64; k++) {
            float xv0 = tp[k][bl];
            float xv1 = tp[k][b2];
            float4 wv = lwp[k * 4 + og];
            a0.x += xv0 * wv.x; a0.y += xv0 * wv.y; a0.z += xv0 * wv.z; a0.w += xv0 * wv.w;
            a1.x += xv1 * wv.x; a1.y += xv1 * wv.y; a1.z += xv1 * wv.z; a1.w += xv1 * wv.w;
        }
    }
    float4* part4 = (float4*)(ws + WS_PART);
    int base = ((c * NRC + rc) * B + bl) * 4 + og;
    part4[base] = a0;
    if (bl < 36) part4[base + 64 * 4] = a1;
}

// ---------- S: reduce 72 partials + squash; writes v (2 layouts) + smut ----------
__global__ __launch_bounds__(256) void k_squash(float* __restrict__ ws,
                                                const float* __restrict__ Wg,
                                                const float* __restrict__ x0,
                                                const float4* __restrict__ x14,
                                                const float4* __restrict__ x24,
                                                float4* __restrict__ out, int ubase) {
    const int t = threadIdx.x;
    if (blockIdx.x >= B) {
        int k = blockIdx.x - B;
        #pragma unroll 1
        for (int n = 0; n < 2; n++)
            stream_unit(ubase + k * 2 + n, (const float4*)Wg, (const float4*)x0, x14, x24, out);
        return;
    }
    const int b = blockIdx.x;
    __shared__ float sl[160];
    __shared__ float nf[C];
    if (t < 160) {
        int c = t >> 4, o = t & 15;
        float s = 0.f;
        const float* p = ws + WS_PART + ((size_t)c * NRC * B + b) * 16 + o;
        #pragma unroll 8
        for (int rc = 0; rc < NRC; rc++) s += p[rc * 1600];
        sl[t] = s;
    }
    __syncthreads();
    if (t < C) {
        float fv[C];
        #pragma unroll
        for (int c2 = 0; c2 < C; c2++) fv[c2] = sl[c2 * O];
        float mine = sl[t * O];
        int rank = 0, i1 = 0, i2 = 0, i3 = 0;
        #pragma unroll
        for (int c2 = 0; c2 < C; c2++) {
            rank += (fv[c2] < mine) || (fv[c2] == mine && c2 < t);
            i1 += fv[c2] < T1c;
            i2 += fv[c2] < 0.0f;
            i3 += fv[c2] < T3c;
        }
        float nv = mine;
        if (i1 > 0 && rank < i1 - 1)                               nv = -0.074520095f * mine + 0.349297946f;
        else if (i2 > 0 && i2 > i1 && rank >= i1 && rank < i2 - 1) nv = -0.534473989f * mine + 0.27196494f;
        else if (i3 > 0 && i3 > i2 && rank >= i2 && rank < i3 - 1) nv = 0.637642944f * mine + 0.295330779f;
        else if (i3 < C && rank >= i3 && rank < C - 1)             nv = 0.169344703f * mine + 0.353784456f;
        nf[t] = nv;
    }
    __syncthreads();
    if (t < 160) {
        int c = t >> 4, o = t & 15;
        float sv = sl[t];
        float nfv = nf[c];
        float smut = (o == 0) ? nfv : sv;
        float v = nfv * smut;
        ws[WS_VBCO + b * 160 + t] = v;
        ws[WS_SMUT + b * 160 + t] = smut;
        ws[WS_VOB + t * B + b] = v;        // [c*16+o][b] for coalesced A staging
    }
}

// ---------- A: agreement; one block per r; coalesced v staging ----------
__global__ __launch_bounds__(256) void k_agree(const float* __restrict__ Wg,
                                               const float* __restrict__ x0,
                                               float* __restrict__ ws,
                                               const float4* __restrict__ x14,
                                               const float4* __restrict__ x24,
                                               float4* __restrict__ out,
                                               int it, int ubase) {
    const int t = threadIdx.x;
    if (blockIdx.x >= R) {
        int k = blockIdx.x - R;
        #pragma unroll 1
        for (int n = 0; n < 3; n++)
            stream_unit(ubase + k * 3 + n, (const float4*)Wg, (const float4*)x0, x14, x24, out);
        return;
    }
    const int r = blockIdx.x;
    __shared__ __align__(16) float vt[3200];   // [cc][b], one 32-co chunk
    __shared__ __align__(16) float xs[800];    // [i][b]
    __shared__ __align__(16) float arr[1280];  // [co][i]
    const float4* x04 = (const float4*)x0;
    if (t < 200) {
        int b = t >> 1, half = t & 1;
        float4 v = x04[(size_t)b * RC2 + r * 2 + half];
        xs[(half * 4 + 0) * B + b] = v.x; xs[(half * 4 + 1) * B + b] = v.y;
        xs[(half * 4 + 2) * B + b] = v.z; xs[(half * 4 + 3) * B + b] = v.w;
    }
    const int i = t & 7, co0 = t >> 3;
    const float4* xs4 = (const float4*)(xs + i * B);
    const float4* vt4 = (const float4*)(vt + co0 * B);
    for (int ch = 0; ch < 5; ch++) {
        __syncthreads();
        for (int j = t; j < 3200; j += 256) vt[j] = ws[WS_VOB + ch * 3200 + j];  // coalesced
        __syncthreads();
        float q = 0.f;
        #pragma unroll
        for (int b4 = 0; b4 < 25; b4++) {
            float4 xv = xs4[b4];
            float4 vv = vt4[b4];
            q += xv.x * vv.x + xv.y * vv.y + xv.z * vv.z + xv.w * vv.w;
        }
        int co = ch * 32 + co0;
        arr[co * I + i] = q * Wg[(size_t)r * 1280 + co * I + i];
    }
    __syncthreads();
    if (t < C) {
        const float4* a4 = (const float4*)(arr + t * 128);
        float d = 0.f;
        #pragma unroll
        for (int m2 = 0; m2 < 32; m2++) { float4 v4 = a4[m2]; d += v4.x + v4.y + v4.z + v4.w; }
        float* dst = ws + WS_BCOL + t * R + r;
        float val = d * (1.0f / B);
        if (it == 0) *dst = val; else *dst += val;
    }
}

// ---------- OUT: v_j | c_full | s_mut regions + remaining stream units ----------
__global__ __launch_bounds__(256) void k_out(const float* __restrict__ x0,
                                             const float* __restrict__ x1,
                                             const float* __restrict__ x2,
                                             float* __restrict__ ws,
                                             const float* __restrict__ Wg,
                                             float4* __restrict__ out) {
    const int bid = blockIdx.x, t = threadIdx.x;
    const float4* cs4 = (const float4*)(ws + WS_CSM);
    const float4* vb4 = (const float4*)(ws + WS_VBCO);
    const float4* sm4 = (const float4*)(ws + WS_SMUT);
    for (int j = bid * 256 + t; j < 296000; j += 2048 * 256) {
        float4 v; int g;
        if (j < 4000)        { v = vb4[j]; g = j; }
        else if (j < 292000) { v = cs4[(j - 4000) % 2880]; g = j; }
        else                 { v = sm4[j - 292000]; g = O_SM + (j - 292000); }
        nt_store4(v, &out[g]);
    }
    if (bid < U_TOT - 6300)
        stream_unit(6300 + bid, (const float4*)Wg, (const float4*)x0,
                    (const float4*)x1, (const float4*)x2, out);
}

extern "C" void kernel_launch(void* const* d_in, const int* in_sizes, int n_in,
                              void* d_out, int out_size, void* d_ws, size_t ws_size,
                              hipStream_t stream) {
    (void)in_sizes; (void)n_in; (void)out_size; (void)ws_size;
    const float* x0 = (const float*)d_in[0];
    const float* x1 = (const float*)d_in[1];
    const float* x2 = (const float*)d_in[2];
    const float* Wg = (const float*)d_in[3];
    const float4* x14 = (const float4*)x1;
    const float4* x24 = (const float4*)x2;
    float* ws = (float*)d_ws;
    float4* out = (float4*)d_out;

    // 9 launches; static stream-unit slices sized ~ duration x BW
    hipLaunchKernelGGL(k_gemm,   dim3(1020), dim3(256), 0, stream, Wg, x0, ws, x14, x24, out, 0, 0);
    hipLaunchKernelGGL(k_squash, dim3(400),  dim3(256), 0, stream, ws, Wg, x0, x14, x24, out, 900);
    hipLaunchKernelGGL(k_agree,  dim3(1452), dim3(256), 0, stream, Wg, x0, ws, x14, x24, out, 0, 1500);
    hipLaunchKernelGGL(k_gemm,   dim3(1020), dim3(256), 0, stream, Wg, x0, ws, x14, x24, out, 1, 2400);
    hipLaunchKernelGGL(k_squash, dim3(400),  dim3(256), 0, stream, ws, Wg, x0, x14, x24, out, 3300);
    hipLaunchKernelGGL(k_agree,  dim3(1452), dim3(256), 0, stream, Wg, x0, ws, x14, x24, out, 1, 3900);
    hipLaunchKernelGGL(k_gemm,   dim3(1020), dim3(256), 0, stream, Wg, x0, ws, x14, x24, out, 2, 4800);
    hipLaunchKernelGGL(k_squash, dim3(400),  dim3(256), 0, stream, ws, Wg, x0, x14, x24, out, 5700);
    hipLaunchKernelGGL(k_out,    dim3(2048), dim3(256), 0, stream, x0, x1, x2, ws, Wg, out);
}

// Round 7
// 223.409 us; speedup vs baseline: 6.1041x; 1.0160x over previous
//
#include <hip/hip_runtime.h>

#define B 100
#define R 1152
#define C 10
#define O 16
#define I 8
#define RI 9216
#define RC2 2304        // x0 row length in float4
#define RCHUNK 16
#define NRC 72          // R / RCHUNK
#define KCH 128         // RCHUNK*I

#define T1c (-0.075410217f)
#define T3c (0.062207676f)

typedef float f4raw __attribute__((ext_vector_type(4)));
static __device__ __forceinline__ void nt_store4(const float4& v, float4* p) {
    __builtin_nontemporal_store(*(const f4raw*)&v, (f4raw*)p);
}

// ws float offsets
#define WS_BCOL 0                  // [c][r] 11520
#define WS_CSM  11520              // [r][c] 11520
#define WS_PART 23040              // [c][rc][b][o] 10*72*100*16 = 1152000
#define WS_VOB  1175040            // [c*16+o][b] 16000 (coalesced A staging)

// out float4 offsets
#define O_VJ 0
#define O_CF 4000
#define O_WB 292000
#define O_SQ 37156000
#define O_X1 39460000
#define O_X2 39690400
#define O_SM 39710000

// static stream units (80KB each): Wb 7200 | squashed_u 563 | x1 57 | x2 5
#define U_WB 7200
#define U_SQ 563
#define U_X1 57
#define U_TOT 7825

__device__ void stream_unit(int u, const float4* __restrict__ W4,
                            const float4* __restrict__ x04,
                            const float4* __restrict__ x14,
                            const float4* __restrict__ x24,
                            float4* __restrict__ out) {
    const int t = threadIdx.x;
    if (u < U_WB) {
        int wchunk = u % 1440, bg = u / 1440;
        int idx = wchunk * 256 + t;
        float4 v = W4[idx];
        float4* dst = out + O_WB + (size_t)bg * 20 * 368640 + idx;
        #pragma unroll
        for (int b = 0; b < 20; b++) { nt_store4(v, dst); dst += 368640; }
    } else if (u < U_WB + U_SQ) {
        int s = u - U_WB;
        int m0 = s * 4096, m1 = m0 + 4096; if (m1 > 2304000) m1 = 2304000;
        for (int m = m0 + t; m < m1; m += 256) {
            float4 v = x04[(m / 20) * 2 + (m & 1)];   // squashed_u = x0 bcast over c
            nt_store4(v, &out[O_SQ + m]);
        }
    } else if (u < U_WB + U_SQ + U_X1) {
        int s = u - U_WB - U_SQ;
        int m0 = s * 4096, m1 = m0 + 4096; if (m1 > 230400) m1 = 230400;
        for (int m = m0 + t; m < m1; m += 256) nt_store4(x14[m], &out[O_X1 + m]);
    } else {
        int s = u - U_WB - U_SQ - U_X1;
        int m0 = s * 4096, m1 = m0 + 4096; if (m1 > 19600) m1 = 19600;
        for (int m = m0 + t; m < m1; m += 256) nt_store4(x24[m], &out[O_X2 + m]);
    }
}

// ---------- G: s_j partial GEMM, softmax fused, k-paired x0 LDS tiles ----------
__global__ __launch_bounds__(256) void k_gemm(const float* __restrict__ Wg,
                                              const float* __restrict__ x0,
                                              float* __restrict__ ws,
                                              const float4* __restrict__ x14,
                                              const float4* __restrict__ x24,
                                              float4* __restrict__ out,
                                              int it, int ubase) {
    const int t = threadIdx.x;
    const float4* x04 = (const float4*)x0;
    if (blockIdx.x >= 720) {
        stream_unit(ubase + (blockIdx.x - 720), (const float4*)Wg, x04, x14, x24, out);
        return;
    }
    const int rc = blockIdx.x % NRC, c = blockIdx.x / NRC;
    const int r0 = rc * RCHUNK;
    __shared__ float red[256];
    __shared__ float cw[RCHUNK];
    __shared__ __align__(16) float lw[KCH * O];   // 2048: [k][o], c-weight folded
    __shared__ float2 tpp[32][104];               // [k2][b]: (k=2*k2, k=2*k2+1)

    if (it > 0) {
        const float* bcol = ws + WS_BCOL + c * R;
        float lm = -3.4e38f;
        for (int r = t; r < R; r += 256) lm = fmaxf(lm, bcol[r]);
        red[t] = lm; __syncthreads();
        for (int s = 128; s > 0; s >>= 1) { if (t < s) red[t] = fmaxf(red[t], red[t + s]); __syncthreads(); }
        const float m = red[0]; __syncthreads();
        float ls = 0.f;
        for (int r = t; r < R; r += 256) ls += expf(bcol[r] - m);
        red[t] = ls; __syncthreads();
        for (int s = 128; s > 0; s >>= 1) { if (t < s) red[t] += red[t + s]; __syncthreads(); }
        const float sinv = 1.f / red[0];
        if (t < RCHUNK) cw[t] = expf(bcol[r0 + t] - m) * sinv;
        if (it == 2 && rc == 0) {   // final c_ij feeds the c_full output
            for (int r = t; r < R; r += 256)
                ws[WS_CSM + r * C + c] = expf(bcol[r] - m) * sinv;
        }
    } else {
        if (t < RCHUNK) cw[t] = 1.0f / 1152.0f;   // softmax of zeros
    }
    __syncthreads();

    // stage c-weighted W slice: lw[(rr*8+i)*16+o] = cw[rr]*W[r0+rr,c,o,i]
    for (int j = t; j < KCH * O; j += 256) {
        int rr = j >> 7;
        int rem = j & 127;            // o*8+i
        int o = rem >> 3, i = rem & 7;
        lw[((rr * I + i) << 4) + o] = cw[rr] * Wg[((size_t)(r0 + rr) * C + c) * 128 + rem];
    }

    const int bl = t & 63, og = t >> 6;
    int b2 = bl + 64; if (b2 > 103) b2 = 103;    // clamps into zero pad
    float4 a0 = {0, 0, 0, 0}, a1 = {0, 0, 0, 0};
    for (int p = 0; p < 2; p++) {
        __syncthreads();   // covers lw staging (p0) / prev-phase reads (p1)
        int colbase = r0 * 2 + p * 16;           // f4 column base in x0 row
        for (int e = t; e < 1600; e += 256) {
            int b = e >> 4, q = e & 15;
            float4 v = x04[(size_t)b * RC2 + colbase + q];
            tpp[q * 2 + 0][b] = make_float2(v.x, v.y);
            tpp[q * 2 + 1][b] = make_float2(v.z, v.w);
        }
        if (p == 0 && t < 128) tpp[t >> 2][100 + (t & 3)] = make_float2(0.f, 0.f);
        __syncthreads();
        const float4* lwp = (const float4*)lw + p * 256;
        #pragma unroll 8
        for (int k2 = 0; k2 < 32; k2++) {
            float2 xv0 = tpp[k2][bl];
            float2 xv1 = tpp[k2][b2];
            float4 wa = lwp[(k2 * 2) * 4 + og];
            float4 wb = lwp[(k2 * 2 + 1) * 4 + og];
            a0.x += xv0.x * wa.x + xv0.y * wb.x;
            a0.y += xv0.x * wa.y + xv0.y * wb.y;
            a0.z += xv0.x * wa.z + xv0.y * wb.z;
            a0.w += xv0.x * wa.w + xv0.y * wb.w;
            a1.x += xv1.x * wa.x + xv1.y * wb.x;
            a1.y += xv1.x * wa.y + xv1.y * wb.y;
            a1.z += xv1.x * wa.z + xv1.y * wb.z;
            a1.w += xv1.x * wa.w + xv1.y * wb.w;
        }
    }
    float4* part4 = (float4*)(ws + WS_PART);
    int base = ((c * NRC + rc) * B + bl) * 4 + og;
    part4[base] = a0;
    if (bl < 36) part4[base + 256] = a1;
}

// ---------- S: reduce 72 partials + squash -> VOB only (A's input) ----------
__global__ __launch_bounds__(256) void k_squash(float* __restrict__ ws,
                                                const float* __restrict__ Wg,
                                                const float* __restrict__ x0,
                                                const float4* __restrict__ x14,
                                                const float4* __restrict__ x24,
                                                float4* __restrict__ out, int ubase) {
    const int t = threadIdx.x;
    if (blockIdx.x >= B) {
        stream_unit(ubase + (blockIdx.x - B), (const float4*)Wg, (const float4*)x0, x14, x24, out);
        return;
    }
    const int b = blockIdx.x;
    __shared__ float sl[160];
    __shared__ float nf[C];
    if (t < 160) {
        int c = t >> 4, o = t & 15;
        float s = 0.f;
        const float* p = ws + WS_PART + ((size_t)c * NRC * B + b) * 16 + o;
        #pragma unroll 8
        for (int rc = 0; rc < NRC; rc++) s += p[rc * 1600];
        sl[t] = s;
    }
    __syncthreads();
    if (t < C) {
        float fv[C];
        #pragma unroll
        for (int c2 = 0; c2 < C; c2++) fv[c2] = sl[c2 * O];
        float mine = sl[t * O];
        int rank = 0, i1 = 0, i2 = 0, i3 = 0;
        #pragma unroll
        for (int c2 = 0; c2 < C; c2++) {
            rank += (fv[c2] < mine) || (fv[c2] == mine && c2 < t);
            i1 += fv[c2] < T1c;
            i2 += fv[c2] < 0.0f;
            i3 += fv[c2] < T3c;
        }
        float nv = mine;
        if (i1 > 0 && rank < i1 - 1)                               nv = -0.074520095f * mine + 0.349297946f;
        else if (i2 > 0 && i2 > i1 && rank >= i1 && rank < i2 - 1) nv = -0.534473989f * mine + 0.27196494f;
        else if (i3 > 0 && i3 > i2 && rank >= i2 && rank < i3 - 1) nv = 0.637642944f * mine + 0.295330779f;
        else if (i3 < C && rank >= i3 && rank < C - 1)             nv = 0.169344703f * mine + 0.353784456f;
        nf[t] = nv;
    }
    __syncthreads();
    if (t < 160) {
        int c = t >> 4, o = t & 15;
        float smut = (o == 0) ? nf[c] : sl[t];
        ws[WS_VOB + t * B + b] = nf[c] * smut;   // [c*16+o][b]
    }
}

// ---------- A: agreement; one block per r; coalesced+vectorized v staging ----------
__global__ __launch_bounds__(256) void k_agree(const float* __restrict__ Wg,
                                               const float* __restrict__ x0,
                                               float* __restrict__ ws,
                                               const float4* __restrict__ x14,
                                               const float4* __restrict__ x24,
                                               float4* __restrict__ out,
                                               int it, int ubase) {
    const int t = threadIdx.x;
    if (blockIdx.x >= R) {
        stream_unit(ubase + (blockIdx.x - R), (const float4*)Wg, (const float4*)x0, x14, x24, out);
        return;
    }
    const int r = blockIdx.x;
    __shared__ __align__(16) float vt[3200];   // [cc][b], one 32-co chunk
    __shared__ __align__(16) float xs[800];    // [i][b]
    __shared__ __align__(16) float arr[1280];  // [co][i]
    const float4* x04 = (const float4*)x0;
    const float4* vob4 = (const float4*)(ws + WS_VOB);
    if (t < 200) {
        int b = t >> 1, half = t & 1;
        float4 v = x04[(size_t)b * RC2 + r * 2 + half];
        xs[(half * 4 + 0) * B + b] = v.x; xs[(half * 4 + 1) * B + b] = v.y;
        xs[(half * 4 + 2) * B + b] = v.z; xs[(half * 4 + 3) * B + b] = v.w;
    }
    const int i = t & 7, co0 = t >> 3;
    const float4* xs4 = (const float4*)(xs + i * B);
    const float4* vt4 = (const float4*)(vt + co0 * B);
    float4* vtw = (float4*)vt;
    for (int ch = 0; ch < 5; ch++) {
        __syncthreads();
        for (int j = t; j < 800; j += 256) vtw[j] = vob4[ch * 800 + j];  // coalesced f4
        __syncthreads();
        float q = 0.f;
        #pragma unroll
        for (int b4 = 0; b4 < 25; b4++) {
            float4 xv = xs4[b4];
            float4 vv = vt4[b4];
            q += xv.x * vv.x + xv.y * vv.y + xv.z * vv.z + xv.w * vv.w;
        }
        int co = ch * 32 + co0;
        arr[co * I + i] = q * Wg[(size_t)r * 1280 + co * I + i];
    }
    __syncthreads();
    if (t < C) {
        const float4* a4 = (const float4*)(arr + t * 128);
        float d = 0.f;
        #pragma unroll
        for (int m2 = 0; m2 < 32; m2++) { float4 v4 = a4[m2]; d += v4.x + v4.y + v4.z + v4.w; }
        float* dst = ws + WS_BCOL + t * R + r;
        float val = d * (1.0f / B);
        if (it == 0) *dst = val; else *dst += val;
    }
}

// ---------- OUT: final squash (blocks 0..99) + c_full + remaining stream units ----------
__global__ __launch_bounds__(256) void k_out(const float* __restrict__ x0,
                                             const float* __restrict__ x1,
                                             const float* __restrict__ x2,
                                             float* __restrict__ ws,
                                             const float* __restrict__ Wg,
                                             float4* __restrict__ out) {
    const int bid = blockIdx.x, t = threadIdx.x;
    if (bid < B) {   // final squash from G2 partials -> v_j + s_mut straight to out
        const int b = bid;
        __shared__ float sl[160];
        __shared__ float nf[C];
        __shared__ __align__(16) float vv[160];
        __shared__ __align__(16) float sm[160];
        if (t < 160) {
            int c = t >> 4, o = t & 15;
            float s = 0.f;
            const float* p = ws + WS_PART + ((size_t)c * NRC * B + b) * 16 + o;
            #pragma unroll 8
            for (int rc = 0; rc < NRC; rc++) s += p[rc * 1600];
            sl[t] = s;
        }
        __syncthreads();
        if (t < C) {
            float fv[C];
            #pragma unroll
            for (int c2 = 0; c2 < C; c2++) fv[c2] = sl[c2 * O];
            float mine = sl[t * O];
            int rank = 0, i1 = 0, i2 = 0, i3 = 0;
            #pragma unroll
            for (int c2 = 0; c2 < C; c2++) {
                rank += (fv[c2] < mine) || (fv[c2] == mine && c2 < t);
                i1 += fv[c2] < T1c;
                i2 += fv[c2] < 0.0f;
                i3 += fv[c2] < T3c;
            }
            float nv = mine;
            if (i1 > 0 && rank < i1 - 1)                               nv = -0.074520095f * mine + 0.349297946f;
            else if (i2 > 0 && i2 > i1 && rank >= i1 && rank < i2 - 1) nv = -0.534473989f * mine + 0.27196494f;
            else if (i3 > 0 && i3 > i2 && rank >= i2 && rank < i3 - 1) nv = 0.637642944f * mine + 0.295330779f;
            else if (i3 < C && rank >= i3 && rank < C - 1)             nv = 0.169344703f * mine + 0.353784456f;
            nf[t] = nv;
        }
        __syncthreads();
        if (t < 160) {
            int c = t >> 4, o = t & 15;
            float smut = (o == 0) ? nf[c] : sl[t];
            sm[t] = smut;
            vv[t] = nf[c] * smut;
        }
        __syncthreads();
        if (t < 40) {
            nt_store4(((const float4*)vv)[t], &out[O_VJ + b * 40 + t]);
            nt_store4(((const float4*)sm)[t], &out[O_SM + b * 40 + t]);
        }
    }
    // c_full (CSM repeated per b)
    const float4* cs4 = (const float4*)(ws + WS_CSM);
    for (int j = bid * 256 + t; j < 288000; j += 2048 * 256)
        nt_store4(cs4[j % 2880], &out[O_CF + j]);
    // remaining stream units
    for (int k = 0; k < 3; k++) {
        int u = 2700 + bid + k * 2048;
        if (u < U_TOT)
            stream_unit(u, (const float4*)Wg, (const float4*)x0,
                        (const float4*)x1, (const float4*)x2, out);
    }
}

extern "C" void kernel_launch(void* const* d_in, const int* in_sizes, int n_in,
                              void* d_out, int out_size, void* d_ws, size_t ws_size,
                              hipStream_t stream) {
    (void)in_sizes; (void)n_in; (void)out_size; (void)ws_size;
    const float* x0 = (const float*)d_in[0];
    const float* x1 = (const float*)d_in[1];
    const float* x2 = (const float*)d_in[2];
    const float* Wg = (const float*)d_in[3];
    const float4* x14 = (const float4*)x1;
    const float4* x24 = (const float4*)x2;
    float* ws = (float*)d_ws;
    float4* out = (float4*)d_out;

    // 8 launches; 1-unit riders; unit bases: G0=0 S0=500 A0=700 G1=1100
    // S1=1600 A1=1800 G2=2200; k_out covers 2700..7824
    hipLaunchKernelGGL(k_gemm,   dim3(720 + 500), dim3(256), 0, stream, Wg, x0, ws, x14, x24, out, 0, 0);
    hipLaunchKernelGGL(k_squash, dim3(100 + 200), dim3(256), 0, stream, ws, Wg, x0, x14, x24, out, 500);
    hipLaunchKernelGGL(k_agree,  dim3(1152 + 400), dim3(256), 0, stream, Wg, x0, ws, x14, x24, out, 0, 700);
    hipLaunchKernelGGL(k_gemm,   dim3(720 + 500), dim3(256), 0, stream, Wg, x0, ws, x14, x24, out, 1, 1100);
    hipLaunchKernelGGL(k_squash, dim3(100 + 200), dim3(256), 0, stream, ws, Wg, x0, x14, x24, out, 1600);
    hipLaunchKernelGGL(k_agree,  dim3(1152 + 400), dim3(256), 0, stream, Wg, x0, ws, x14, x24, out, 1, 1800);
    hipLaunchKernelGGL(k_gemm,   dim3(720 + 500), dim3(256), 0, stream, Wg, x0, ws, x14, x24, out, 2, 2200);
    hipLaunchKernelGGL(k_out,    dim3(2048), dim3(256), 0, stream, x0, x1, x2, ws, Wg, out);
}

// Round 8
// 205.588 us; speedup vs baseline: 6.6333x; 1.0867x over previous
//
#include <hip/hip_runtime.h>

#define B 100
#define R 1152
#define C 10
#define O 16
#define I 8
#define RI 9216
#define RC2 2304        // x0 row length in float4
#define RCHUNK 16
#define NRC 72          // R / RCHUNK
#define KCH 128         // RCHUNK*I

#define T1c (-0.075410217f)
#define T3c (0.062207676f)

typedef float f4raw __attribute__((ext_vector_type(4)));
static __device__ __forceinline__ void nt_store4(const float4& v, float4* p) {
    __builtin_nontemporal_store(*(const f4raw*)&v, (f4raw*)p);
}

// ws float offsets
#define WS_BCOL 0                  // [c][r] 11520
#define WS_CSM  11520              // [r][c] 11520
#define WS_PART 23040              // [c][rc][b][o] 10*72*100*16 = 1152000
#define WS_VOB  1175040            // [c*16+o][b] 16000 (coalesced A staging)

// out float4 offsets
#define O_VJ 0
#define O_CF 4000
#define O_WB 292000
#define O_SQ 37156000
#define O_X1 39460000
#define O_X2 39690400
#define O_SM 39710000

// static stream units (80KB each): Wb 7200 | squashed_u 563 | x1 57 | x2 5
#define U_WB 7200
#define U_SQ 563
#define U_X1 57
#define U_TOT 7825

__device__ void stream_unit(int u, const float4* __restrict__ W4,
                            const float4* __restrict__ x04,
                            const float4* __restrict__ x14,
                            const float4* __restrict__ x24,
                            float4* __restrict__ out) {
    const int t = threadIdx.x;
    if (u < U_WB) {
        int wchunk = u % 1440, bg = u / 1440;
        int idx = wchunk * 256 + t;
        float4 v = W4[idx];
        float4* dst = out + O_WB + (size_t)bg * 20 * 368640 + idx;
        #pragma unroll
        for (int b = 0; b < 20; b++) { nt_store4(v, dst); dst += 368640; }
    } else if (u < U_WB + U_SQ) {
        int s = u - U_WB;
        int m0 = s * 4096, m1 = m0 + 4096; if (m1 > 2304000) m1 = 2304000;
        for (int m = m0 + t; m < m1; m += 256) {
            float4 v = x04[(m / 20) * 2 + (m & 1)];   // squashed_u = x0 bcast over c
            nt_store4(v, &out[O_SQ + m]);
        }
    } else if (u < U_WB + U_SQ + U_X1) {
        int s = u - U_WB - U_SQ;
        int m0 = s * 4096, m1 = m0 + 4096; if (m1 > 230400) m1 = 230400;
        for (int m = m0 + t; m < m1; m += 256) nt_store4(x14[m], &out[O_X1 + m]);
    } else {
        int s = u - U_WB - U_SQ - U_X1;
        int m0 = s * 4096, m1 = m0 + 4096; if (m1 > 19600) m1 = 19600;
        for (int m = m0 + t; m < m1; m += 256) nt_store4(x24[m], &out[O_X2 + m]);
    }
}

// ---------- G: s_j partial GEMM, softmax fused; 4-phase x0 tiles (22KB LDS) ----------
__global__ __launch_bounds__(256) void k_gemm(const float* __restrict__ Wg,
                                              const float* __restrict__ x0,
                                              float* __restrict__ ws,
                                              const float4* __restrict__ x14,
                                              const float4* __restrict__ x24,
                                              float4* __restrict__ out,
                                              int it, int ubase) {
    const int t = threadIdx.x;
    const float4* x04 = (const float4*)x0;
    if (blockIdx.x >= 720) {
        stream_unit(ubase + (blockIdx.x - 720), (const float4*)Wg, x04, x14, x24, out);
        return;
    }
    const int rc = blockIdx.x % NRC, c = blockIdx.x / NRC;
    const int r0 = rc * RCHUNK;
    __shared__ float red[256];
    __shared__ float cw[RCHUNK];
    __shared__ __align__(16) float lw[KCH * O];   // 2048: [k][o], c-weight folded
    __shared__ float2 tpp[16][104];               // [k2 local][b]; 13.3 KB

    if (it > 0) {
        const float* bcol = ws + WS_BCOL + c * R;
        float lm = -3.4e38f;
        for (int r = t; r < R; r += 256) lm = fmaxf(lm, bcol[r]);
        red[t] = lm; __syncthreads();
        for (int s = 128; s > 0; s >>= 1) { if (t < s) red[t] = fmaxf(red[t], red[t + s]); __syncthreads(); }
        const float m = red[0]; __syncthreads();
        float ls = 0.f;
        for (int r = t; r < R; r += 256) ls += expf(bcol[r] - m);
        red[t] = ls; __syncthreads();
        for (int s = 128; s > 0; s >>= 1) { if (t < s) red[t] += red[t + s]; __syncthreads(); }
        const float sinv = 1.f / red[0];
        if (t < RCHUNK) cw[t] = expf(bcol[r0 + t] - m) * sinv;
        if (it == 2 && rc == 0) {   // final c_ij feeds the c_full output
            for (int r = t; r < R; r += 256)
                ws[WS_CSM + r * C + c] = expf(bcol[r] - m) * sinv;
        }
    } else {
        if (t < RCHUNK) cw[t] = 1.0f / 1152.0f;   // softmax of zeros
    }
    __syncthreads();

    // stage c-weighted W slice: lw[(rr*8+i)*16+o] = cw[rr]*W[r0+rr,c,o,i]
    for (int j = t; j < KCH * O; j += 256) {
        int rr = j >> 7;
        int rem = j & 127;            // o*8+i
        int o = rem >> 3, i = rem & 7;
        lw[((rr * I + i) << 4) + o] = cw[rr] * Wg[((size_t)(r0 + rr) * C + c) * 128 + rem];
    }

    const int bl = t & 63, og = t >> 6;
    int b2 = bl + 64; if (b2 > 103) b2 = 103;    // clamps into zero pad
    float4 a0 = {0, 0, 0, 0}, a1 = {0, 0, 0, 0};
    for (int p = 0; p < 4; p++) {
        __syncthreads();   // covers lw staging (p0) / prev-phase reads
        int colbase = r0 * 2 + p * 8;            // 8 f4 (=32 k) per phase
        for (int e = t; e < 800; e += 256) {
            int b = e >> 3, q = e & 7;
            float4 v = x04[(size_t)b * RC2 + colbase + q];
            tpp[q * 2 + 0][b] = make_float2(v.x, v.y);
            tpp[q * 2 + 1][b] = make_float2(v.z, v.w);
        }
        if (p == 0 && t < 64) tpp[t >> 2][100 + (t & 3)] = make_float2(0.f, 0.f);
        __syncthreads();
        const float4* lwp = (const float4*)lw + p * 128;
        #pragma unroll 8
        for (int k2 = 0; k2 < 16; k2++) {
            float2 xv0 = tpp[k2][bl];
            float2 xv1 = tpp[k2][b2];
            float4 wa = lwp[k2 * 8 + og];
            float4 wb = lwp[k2 * 8 + 4 + og];
            a0.x += xv0.x * wa.x + xv0.y * wb.x;
            a0.y += xv0.x * wa.y + xv0.y * wb.y;
            a0.z += xv0.x * wa.z + xv0.y * wb.z;
            a0.w += xv0.x * wa.w + xv0.y * wb.w;
            a1.x += xv1.x * wa.x + xv1.y * wb.x;
            a1.y += xv1.x * wa.y + xv1.y * wb.y;
            a1.z += xv1.x * wa.z + xv1.y * wb.z;
            a1.w += xv1.x * wa.w + xv1.y * wb.w;
        }
    }
    float4* part4 = (float4*)(ws + WS_PART);
    int base = ((c * NRC + rc) * B + bl) * 4 + og;
    part4[base] = a0;
    if (bl < 36) part4[base + 256] = a1;
}

// ---------- S: reduce 72 partials + squash -> VOB only (A's input) ----------
__global__ __launch_bounds__(256) void k_squash(float* __restrict__ ws,
                                                const float* __restrict__ Wg,
                                                const float* __restrict__ x0,
                                                const float4* __restrict__ x14,
                                                const float4* __restrict__ x24,
                                                float4* __restrict__ out, int ubase) {
    const int t = threadIdx.x;
    if (blockIdx.x >= B) {
        stream_unit(ubase + (blockIdx.x - B), (const float4*)Wg, (const float4*)x0, x14, x24, out);
        return;
    }
    const int b = blockIdx.x;
    __shared__ float sl[160];
    __shared__ float nf[C];
    if (t < 160) {
        int c = t >> 4, o = t & 15;
        float s = 0.f;
        const float* p = ws + WS_PART + ((size_t)c * NRC * B + b) * 16 + o;
        #pragma unroll 8
        for (int rc = 0; rc < NRC; rc++) s += p[rc * 1600];
        sl[t] = s;
    }
    __syncthreads();
    if (t < C) {
        float fv[C];
        #pragma unroll
        for (int c2 = 0; c2 < C; c2++) fv[c2] = sl[c2 * O];
        float mine = sl[t * O];
        int rank = 0, i1 = 0, i2 = 0, i3 = 0;
        #pragma unroll
        for (int c2 = 0; c2 < C; c2++) {
            rank += (fv[c2] < mine) || (fv[c2] == mine && c2 < t);
            i1 += fv[c2] < T1c;
            i2 += fv[c2] < 0.0f;
            i3 += fv[c2] < T3c;
        }
        float nv = mine;
        if (i1 > 0 && rank < i1 - 1)                               nv = -0.074520095f * mine + 0.349297946f;
        else if (i2 > 0 && i2 > i1 && rank >= i1 && rank < i2 - 1) nv = -0.534473989f * mine + 0.27196494f;
        else if (i3 > 0 && i3 > i2 && rank >= i2 && rank < i3 - 1) nv = 0.637642944f * mine + 0.295330779f;
        else if (i3 < C && rank >= i3 && rank < C - 1)             nv = 0.169344703f * mine + 0.353784456f;
        nf[t] = nv;
    }
    __syncthreads();
    if (t < 160) {
        int c = t >> 4, o = t & 15;
        float smut = (o == 0) ? nf[c] : sl[t];
        ws[WS_VOB + t * B + b] = nf[c] * smut;   // [c*16+o][b]
    }
}

// ---------- A: agreement; one block per r; coalesced+vectorized v staging ----------
__global__ __launch_bounds__(256) void k_agree(const float* __restrict__ Wg,
                                               const float* __restrict__ x0,
                                               float* __restrict__ ws,
                                               const float4* __restrict__ x14,
                                               const float4* __restrict__ x24,
                                               float4* __restrict__ out,
                                               int it, int ubase) {
    const int t = threadIdx.x;
    if (blockIdx.x >= R) {
        stream_unit(ubase + (blockIdx.x - R), (const float4*)Wg, (const float4*)x0, x14, x24, out);
        return;
    }
    const int r = blockIdx.x;
    __shared__ __align__(16) float vt[3200];   // [cc][b], one 32-co chunk
    __shared__ __align__(16) float xs[800];    // [i][b]
    __shared__ __align__(16) float arr[1280];  // [co][i]
    const float4* x04 = (const float4*)x0;
    const float4* vob4 = (const float4*)(ws + WS_VOB);
    if (t < 200) {
        int b = t >> 1, half = t & 1;
        float4 v = x04[(size_t)b * RC2 + r * 2 + half];
        xs[(half * 4 + 0) * B + b] = v.x; xs[(half * 4 + 1) * B + b] = v.y;
        xs[(half * 4 + 2) * B + b] = v.z; xs[(half * 4 + 3) * B + b] = v.w;
    }
    const int i = t & 7, co0 = t >> 3;
    const float4* xs4 = (const float4*)(xs + i * B);
    const float4* vt4 = (const float4*)(vt + co0 * B);
    float4* vtw = (float4*)vt;
    for (int ch = 0; ch < 5; ch++) {
        __syncthreads();
        for (int j = t; j < 800; j += 256) vtw[j] = vob4[ch * 800 + j];  // coalesced f4
        __syncthreads();
        float q = 0.f;
        #pragma unroll
        for (int b4 = 0; b4 < 25; b4++) {
            float4 xv = xs4[b4];
            float4 vv = vt4[b4];
            q += xv.x * vv.x + xv.y * vv.y + xv.z * vv.z + xv.w * vv.w;
        }
        int co = ch * 32 + co0;
        arr[co * I + i] = q * Wg[(size_t)r * 1280 + co * I + i];
    }
    __syncthreads();
    if (t < C) {
        const float4* a4 = (const float4*)(arr + t * 128);
        float d = 0.f;
        #pragma unroll
        for (int m2 = 0; m2 < 32; m2++) { float4 v4 = a4[m2]; d += v4.x + v4.y + v4.z + v4.w; }
        float* dst = ws + WS_BCOL + t * R + r;
        float val = d * (1.0f / B);
        if (it == 0) *dst = val; else *dst += val;
    }
}

// ---------- OUT: final squash (blocks 0..99) + c_full + remaining stream units ----------
__global__ __launch_bounds__(256) void k_out(const float* __restrict__ x0,
                                             const float* __restrict__ x1,
                                             const float* __restrict__ x2,
                                             float* __restrict__ ws,
                                             const float* __restrict__ Wg,
                                             float4* __restrict__ out) {
    const int bid = blockIdx.x, t = threadIdx.x;
    if (bid < B) {   // final squash from G2 partials -> v_j + s_mut straight to out
        const int b = bid;
        __shared__ float sl[160];
        __shared__ float nf[C];
        __shared__ __align__(16) float vv[160];
        __shared__ __align__(16) float sm[160];
        if (t < 160) {
            int c = t >> 4, o = t & 15;
            float s = 0.f;
            const float* p = ws + WS_PART + ((size_t)c * NRC * B + b) * 16 + o;
            #pragma unroll 8
            for (int rc = 0; rc < NRC; rc++) s += p[rc * 1600];
            sl[t] = s;
        }
        __syncthreads();
        if (t < C) {
            float fv[C];
            #pragma unroll
            for (int c2 = 0; c2 < C; c2++) fv[c2] = sl[c2 * O];
            float mine = sl[t * O];
            int rank = 0, i1 = 0, i2 = 0, i3 = 0;
            #pragma unroll
            for (int c2 = 0; c2 < C; c2++) {
                rank += (fv[c2] < mine) || (fv[c2] == mine && c2 < t);
                i1 += fv[c2] < T1c;
                i2 += fv[c2] < 0.0f;
                i3 += fv[c2] < T3c;
            }
            float nv = mine;
            if (i1 > 0 && rank < i1 - 1)                               nv = -0.074520095f * mine + 0.349297946f;
            else if (i2 > 0 && i2 > i1 && rank >= i1 && rank < i2 - 1) nv = -0.534473989f * mine + 0.27196494f;
            else if (i3 > 0 && i3 > i2 && rank >= i2 && rank < i3 - 1) nv = 0.637642944f * mine + 0.295330779f;
            else if (i3 < C && rank >= i3 && rank < C - 1)             nv = 0.169344703f * mine + 0.353784456f;
            nf[t] = nv;
        }
        __syncthreads();
        if (t < 160) {
            int c = t >> 4, o = t & 15;
            float smut = (o == 0) ? nf[c] : sl[t];
            sm[t] = smut;
            vv[t] = nf[c] * smut;
        }
        __syncthreads();
        if (t < 40) {
            nt_store4(((const float4*)vv)[t], &out[O_VJ + b * 40 + t]);
            nt_store4(((const float4*)sm)[t], &out[O_SM + b * 40 + t]);
        }
    }
    // c_full (CSM repeated per b)
    const float4* cs4 = (const float4*)(ws + WS_CSM);
    for (int j = bid * 256 + t; j < 288000; j += 2048 * 256)
        nt_store4(cs4[j % 2880], &out[O_CF + j]);
    // remaining stream units
    for (int k = 0; k < 2; k++) {
        int u = 4100 + bid + k * 2048;
        if (u < U_TOT)
            stream_unit(u, (const float4*)Wg, (const float4*)x0,
                        (const float4*)x1, (const float4*)x2, out);
    }
}

extern "C" void kernel_launch(void* const* d_in, const int* in_sizes, int n_in,
                              void* d_out, int out_size, void* d_ws, size_t ws_size,
                              hipStream_t stream) {
    (void)in_sizes; (void)n_in; (void)out_size; (void)ws_size;
    const float* x0 = (const float*)d_in[0];
    const float* x1 = (const float*)d_in[1];
    const float* x2 = (const float*)d_in[2];
    const float* Wg = (const float*)d_in[3];
    const float4* x14 = (const float4*)x1;
    const float4* x24 = (const float4*)x2;
    float* ws = (float*)d_ws;
    float4* out = (float4*)d_out;

    // 8 launches; 1-unit riders, single scheduling round per launch.
    // unit bases: G0=0(700) S0=700(400) A0=1100(600) G1=1700(700)
    // S1=2400(400) A1=2800(600) G2=3400(700); k_out covers 4100..7824
    hipLaunchKernelGGL(k_gemm,   dim3(720 + 700), dim3(256), 0, stream, Wg, x0, ws, x14, x24, out, 0, 0);
    hipLaunchKernelGGL(k_squash, dim3(100 + 400), dim3(256), 0, stream, ws, Wg, x0, x14, x24, out, 700);
    hipLaunchKernelGGL(k_agree,  dim3(1152 + 600), dim3(256), 0, stream, Wg, x0, ws, x14, x24, out, 0, 1100);
    hipLaunchKernelGGL(k_gemm,   dim3(720 + 700), dim3(256), 0, stream, Wg, x0, ws, x14, x24, out, 1, 1700);
    hipLaunchKernelGGL(k_squash, dim3(100 + 400), dim3(256), 0, stream, ws, Wg, x0, x14, x24, out, 2400);
    hipLaunchKernelGGL(k_agree,  dim3(1152 + 600), dim3(256), 0, stream, Wg, x0, ws, x14, x24, out, 1, 2800);
    hipLaunchKernelGGL(k_gemm,   dim3(720 + 700), dim3(256), 0, stream, Wg, x0, ws, x14, x24, out, 2, 3400);
    hipLaunchKernelGGL(k_out,    dim3(2048), dim3(256), 0, stream, x0, x1, x2, ws, Wg, out);
}